// Round 4
// baseline (136.317 us; speedup 1.0000x reference)
//
#include <hip/hip_runtime.h>

#define B_  16
#define LQ  256
#define LK  256
#define QD  256
#define HD  128
#define VD  128

// 2*log2(e): exp2(SCALE2*x) = e^{2x}
#define SCALE2 2.8853900817779268f
#define L2E    1.4426950408889634f
#define CTX_SIZE (B_ * LK * VD)

typedef float v2f __attribute__((ext_vector_type(2)));

__device__ __forceinline__ float fast_exp2(float x) { return __builtin_amdgcn_exp2f(x); }
__device__ __forceinline__ float fast_rcp(float x)  { return __builtin_amdgcn_rcpf(x); }

// ---------------------------------------------------------------------------
// proj_kernel: 1024 blocks x 256 threads (unchanged — known-good).
//   blocks [0,512):   qe_t[b][h][q] = exp2(SCALE2 * (query @ Wq))   (transposed)
//   blocks [512,1024): ke[b][k][h]  = exp2(SCALE2 * (key @ Wk))
// ---------------------------------------------------------------------------
__global__ __launch_bounds__(256) void proj_kernel(const float* __restrict__ query,
                                                   const float* __restrict__ key,
                                                   const float* __restrict__ Wq,
                                                   const float* __restrict__ Wk,
                                                   float* __restrict__ qe_t,
                                                   float* __restrict__ ke)
{
    __shared__ float  Xs[8][260];        // 8 rows x full K (=256), padded
    __shared__ float4 part[4][8][32];    // [wave][m][h-group] partial sums

    const int t = threadIdx.x;
    const bool isQ = (blockIdx.x < 512);
    const int blk  = isQ ? blockIdx.x : (blockIdx.x - 512);
    const int rows0 = blk * 8;
    const float* X = isQ ? query : key;
    const float* W = isQ ? Wq : Wk;

    // ---- stage X tile: 8 rows x 256 k (8 KB) ----
    {
        const int r = t >> 5;            // 0..7
        const int c = (t & 31) * 8;      // 0..248
        const float4 x0 = *(const float4*)(X + (size_t)(rows0 + r) * QD + c);
        const float4 x1 = *(const float4*)(X + (size_t)(rows0 + r) * QD + c + 4);
        *(float4*)&Xs[r][c]     = x0;
        *(float4*)&Xs[r][c + 4] = x1;
    }
    __syncthreads();

    const int w    = t >> 6;
    const int lane = t & 63;
    const int hg   = lane & 31;          // h4 = hg*4
    const int mb   = lane >> 5;          // 0/1; lane covers m = mb, mb+2, mb+4, mb+6

    float4 acc[4];
#pragma unroll
    for (int i = 0; i < 4; i++) acc[i] = make_float4(0.f, 0.f, 0.f, 0.f);

    const int kbase = w * 64;
#pragma unroll 4
    for (int kk = 0; kk < 64; kk++) {
        const int k = kbase + kk;
        const float4 wv = *(const float4*)(W + (size_t)k * HD + hg * 4);
#pragma unroll
        for (int mi = 0; mi < 4; mi++) {
            const float xv = Xs[mb + mi * 2][k];
            acc[mi].x += xv * wv.x;
            acc[mi].y += xv * wv.y;
            acc[mi].z += xv * wv.z;
            acc[mi].w += xv * wv.w;
        }
    }
#pragma unroll
    for (int mi = 0; mi < 4; mi++) part[w][mb + mi * 2][hg] = acc[mi];
    __syncthreads();

    // ---- reduce 4 partials, exp, store ----
    {
        const int m   = t >> 5;          // 0..7
        const int hg2 = t & 31;          // 0..31
        float4 s = part[0][m][hg2];
        const float4 p1 = part[1][m][hg2];
        const float4 p2 = part[2][m][hg2];
        const float4 p3 = part[3][m][hg2];
        s.x += p1.x + p2.x + p3.x;
        s.y += p1.y + p2.y + p3.y;
        s.z += p1.z + p2.z + p3.z;
        s.w += p1.w + p2.w + p3.w;
        float4 e = make_float4(fast_exp2(s.x * SCALE2), fast_exp2(s.y * SCALE2),
                               fast_exp2(s.z * SCALE2), fast_exp2(s.w * SCALE2));
        const int row = rows0 + m;
        if (isQ) {
            const int b = row >> 8, q = row & 255;
            float* base = qe_t + ((size_t)b * HD + hg2 * 4) * LQ + q;
            base[0 * LQ] = e.x;
            base[1 * LQ] = e.y;
            base[2 * LQ] = e.z;
            base[3 * LQ] = e.w;
        } else {
            *(float4*)(ke + (size_t)row * HD + hg2 * 4) = e;
        }
    }
}

// ---------------------------------------------------------------------------
// attn_kernel v4: 1024 blocks x 512 threads. Block = (b, 4 consecutive k).
//  - h-split: thread group hh = t>>8 handles h in [hh*64, hh*64+64).
//    Work, qv traffic, ke traffic all CONSERVED vs v3, but waves/CU 16 -> 32
//    (100% occupancy) for latency hiding. v2's k-tile-8 mistake traded
//    traffic for occupancy; this trades nothing.
// Phase 1: thread (q, hh): partial[k][q] += v[h]*rcp(1 + qe[h][q]*ke[k][h])
// Phase 2: waves 0-3: sum halves, softmax over q for k=w; write attn + attn_T
// Phase 3: 8 waves: wave w -> q-range [w*32, w*32+32), all 4 k; reduce -> ctx
// ---------------------------------------------------------------------------
__global__ __launch_bounds__(512, 8) void attn_kernel(const float* __restrict__ qe_t,
                                                      const float* __restrict__ ke,
                                                      const float* __restrict__ v,
                                                      const float* __restrict__ value,
                                                      float* __restrict__ out)
{
    __shared__ float  score_s[2][4][258];  // [h-half][k][q] partial sums
    __shared__ float  attn_T[256][4];      // [q][k] -> float4 row per q
    __shared__ float2 partc[8][4][64];     // [wave][k][vd-pair]

    const int t  = threadIdx.x;
    const int b  = blockIdx.x >> 6;
    const int k0 = (blockIdx.x & 63) << 2;

    const float* qeb = qe_t + (size_t)b * HD * LQ;        // [h][q], holds e^{2qp}
    const float* keb = ke + ((size_t)b * LK + k0) * HD;   // 4 rows, e^{2kp}

    const int q     = t & 255;
    const int hbase = (t >> 8) * 64;      // 0 or 64

    // ---- Phase 1: partial over 64 h ----
    v2f acc[4];
#pragma unroll
    for (int i = 0; i < 4; i++) acc[i] = (v2f)0.f;

#pragma unroll 2
    for (int h0 = 0; h0 < 64; h0 += 8) {
        const int hA = hbase + h0;
        float qv[8];
#pragma unroll
        for (int j = 0; j < 8; j++) qv[j] = qeb[(size_t)(hA + j) * LQ + q];
#pragma unroll
        for (int jp = 0; jp < 4; jp++) {
            v2f q2; q2.x = qv[2 * jp]; q2.y = qv[2 * jp + 1];
            const v2f vh2 = *(const v2f*)(v + hA + 2 * jp);          // uniform
#pragma unroll
            for (int kk = 0; kk < 4; kk++) {
                const v2f ke2 = *(const v2f*)(keb + kk * HD + hA + 2 * jp); // uniform
                v2f tt = __builtin_elementwise_fma(q2, ke2, (v2f)1.0f);
                v2f r; r.x = fast_rcp(tt.x); r.y = fast_rcp(tt.y);
                acc[kk] = __builtin_elementwise_fma(vh2, r, acc[kk]);
            }
        }
    }
    const int hh = t >> 8;
#pragma unroll
    for (int kk = 0; kk < 4; kk++)
        score_s[hh][kk][q] = acc[kk].x + acc[kk].y;
    __syncthreads();

    // ---- Phase 2: waves 0-3 only; softmax over q for k = w ----
    const int w = t >> 6, lane = t & 63;
    if (w < 4) {
        float sumv = 0.f;  // wave-uniform, scalar pipe
#pragma unroll
        for (int h = 0; h < HD; h++) sumv += v[h];
        float x0 = sumv - 2.f * (score_s[0][w][lane]       + score_s[1][w][lane]);
        float x1 = sumv - 2.f * (score_s[0][w][lane + 64]  + score_s[1][w][lane + 64]);
        float x2 = sumv - 2.f * (score_s[0][w][lane + 128] + score_s[1][w][lane + 128]);
        float x3 = sumv - 2.f * (score_s[0][w][lane + 192] + score_s[1][w][lane + 192]);
        float m = fmaxf(fmaxf(x0, x1), fmaxf(x2, x3));
#pragma unroll
        for (int off = 32; off >= 1; off >>= 1) m = fmaxf(m, __shfl_xor(m, off));
        float e0 = fast_exp2((x0 - m) * L2E);
        float e1 = fast_exp2((x1 - m) * L2E);
        float e2 = fast_exp2((x2 - m) * L2E);
        float e3 = fast_exp2((x3 - m) * L2E);
        float s = e0 + e1 + e2 + e3;
#pragma unroll
        for (int off = 32; off >= 1; off >>= 1) s += __shfl_xor(s, off);
        const float rs = fast_rcp(s);
        e0 *= rs; e1 *= rs; e2 *= rs; e3 *= rs;
        attn_T[lane][w]       = e0;
        attn_T[lane + 64][w]  = e1;
        attn_T[lane + 128][w] = e2;
        attn_T[lane + 192][w] = e3;
        float* ao = out + CTX_SIZE + ((size_t)(b * LK + k0 + w)) * LQ;
        ao[lane]       = e0;
        ao[lane + 64]  = e1;
        ao[lane + 128] = e2;
        ao[lane + 192] = e3;
    }
    __syncthreads();

    // ---- Phase 3: context. Wave w sums q-range [w*32, w*32+32) for all 4 k ----
    {
        const int vd2 = lane * 2;
        const float* valb = value + (size_t)b * LQ * VD;
        v2f c0 = (v2f)0.f, c1 = (v2f)0.f, c2 = (v2f)0.f, c3 = (v2f)0.f;
#pragma unroll 4
        for (int i = 0; i < 32; i++) {
            const int q2 = (w << 5) + i;
            const float4 a = *(const float4*)&attn_T[q2][0];    // uniform -> broadcast
            const v2f vv = *(const v2f*)(valb + (size_t)q2 * VD + vd2);
            c0 = __builtin_elementwise_fma((v2f)(a.x), vv, c0);
            c1 = __builtin_elementwise_fma((v2f)(a.y), vv, c1);
            c2 = __builtin_elementwise_fma((v2f)(a.z), vv, c2);
            c3 = __builtin_elementwise_fma((v2f)(a.w), vv, c3);
        }
        partc[w][0][lane] = *(const float2*)&c0;
        partc[w][1][lane] = *(const float2*)&c1;
        partc[w][2][lane] = *(const float2*)&c2;
        partc[w][3][lane] = *(const float2*)&c3;
    }
    __syncthreads();
    if (t < 256) {
        const int kg = t >> 6, l2 = t & 63;
        float2 s = partc[0][kg][l2];
#pragma unroll
        for (int p = 1; p < 8; p++) {
            const float2 pp = partc[p][kg][l2];
            s.x += pp.x;
            s.y += pp.y;
        }
        *(float2*)(out + ((size_t)(b * LK + k0 + kg)) * VD + l2 * 2) = s;
    }
}

extern "C" void kernel_launch(void* const* d_in, const int* in_sizes, int n_in,
                              void* d_out, int out_size, void* d_ws, size_t ws_size,
                              hipStream_t stream)
{
    const float* query = (const float*)d_in[0];
    const float* key   = (const float*)d_in[1];
    const float* value = (const float*)d_in[2];
    const float* Wq    = (const float*)d_in[3];
    const float* Wk    = (const float*)d_in[4];
    const float* v     = (const float*)d_in[5];
    float* out = (float*)d_out;

    float* qe_t = (float*)d_ws;                      // [B][HD][LQ], e^{2qp}
    float* kew  = qe_t + (size_t)B_ * HD * LQ;       // [B][LK][HD], e^{2kp}

    proj_kernel<<<dim3(1024), 256, 0, stream>>>(query, key, Wq, Wk, qe_t, kew);
    attn_kernel<<<dim3(1024), 512, 0, stream>>>(qe_t, kew, v, value, out);
}

// Round 5
// 106.014 us; speedup vs baseline: 1.2858x; 1.2858x over previous
//
#include <hip/hip_runtime.h>

#define B_  16
#define LQ  256
#define LK  256
#define QD  256
#define HD  128
#define VD  128

// 2*log2(e): exp2(SCALE2*x) = e^{2x}
#define SCALE2 2.8853900817779268f
#define L2E    1.4426950408889634f
#define CTX_SIZE (B_ * LK * VD)

typedef float v2f __attribute__((ext_vector_type(2)));

__device__ __forceinline__ float fast_exp2(float x) { return __builtin_amdgcn_exp2f(x); }
__device__ __forceinline__ float fast_rcp(float x)  { return __builtin_amdgcn_rcpf(x); }

// ---------------------------------------------------------------------------
// proj_kernel: 1024 blocks x 256 threads.
//   blocks [0,512):   qe4[b][h/4][q][4] = exp2(SCALE2 * (query @ Wq))
//                     (h-grouped-by-4 layout: one coalesced float4 store here,
//                      and float4 qv loads in attn phase 1)
//   blocks [512,1024): ke[b][k][h]  = exp2(SCALE2 * (key @ Wk))
// ---------------------------------------------------------------------------
__global__ __launch_bounds__(256) void proj_kernel(const float* __restrict__ query,
                                                   const float* __restrict__ key,
                                                   const float* __restrict__ Wq,
                                                   const float* __restrict__ Wk,
                                                   float* __restrict__ qe_t,
                                                   float* __restrict__ ke)
{
    __shared__ float  Xs[8][260];        // 8 rows x full K (=256), padded
    __shared__ float4 part[4][8][32];    // [wave][m][h-group] partial sums

    const int t = threadIdx.x;
    const bool isQ = (blockIdx.x < 512);
    const int blk  = isQ ? blockIdx.x : (blockIdx.x - 512);
    const int rows0 = blk * 8;
    const float* X = isQ ? query : key;
    const float* W = isQ ? Wq : Wk;

    // ---- stage X tile: 8 rows x 256 k (8 KB) ----
    {
        const int r = t >> 5;            // 0..7
        const int c = (t & 31) * 8;      // 0..248
        const float4 x0 = *(const float4*)(X + (size_t)(rows0 + r) * QD + c);
        const float4 x1 = *(const float4*)(X + (size_t)(rows0 + r) * QD + c + 4);
        *(float4*)&Xs[r][c]     = x0;
        *(float4*)&Xs[r][c + 4] = x1;
    }
    __syncthreads();

    const int w    = t >> 6;
    const int lane = t & 63;
    const int hg   = lane & 31;          // h4 = hg*4
    const int mb   = lane >> 5;          // 0/1; lane covers m = mb, mb+2, mb+4, mb+6

    float4 acc[4];
#pragma unroll
    for (int i = 0; i < 4; i++) acc[i] = make_float4(0.f, 0.f, 0.f, 0.f);

    const int kbase = w * 64;
#pragma unroll 4
    for (int kk = 0; kk < 64; kk++) {
        const int k = kbase + kk;
        const float4 wv = *(const float4*)(W + (size_t)k * HD + hg * 4);
#pragma unroll
        for (int mi = 0; mi < 4; mi++) {
            const float xv = Xs[mb + mi * 2][k];
            acc[mi].x += xv * wv.x;
            acc[mi].y += xv * wv.y;
            acc[mi].z += xv * wv.z;
            acc[mi].w += xv * wv.w;
        }
    }
#pragma unroll
    for (int mi = 0; mi < 4; mi++) part[w][mb + mi * 2][hg] = acc[mi];
    __syncthreads();

    // ---- reduce 4 partials, exp, store ----
    {
        const int m   = t >> 5;          // 0..7
        const int hg2 = t & 31;          // 0..31  (covers h = hg2*4 .. +3)
        float4 s = part[0][m][hg2];
        const float4 p1 = part[1][m][hg2];
        const float4 p2 = part[2][m][hg2];
        const float4 p3 = part[3][m][hg2];
        s.x += p1.x + p2.x + p3.x;
        s.y += p1.y + p2.y + p3.y;
        s.z += p1.z + p2.z + p3.z;
        s.w += p1.w + p2.w + p3.w;
        float4 e = make_float4(fast_exp2(s.x * SCALE2), fast_exp2(s.y * SCALE2),
                               fast_exp2(s.z * SCALE2), fast_exp2(s.w * SCALE2));
        const int row = rows0 + m;
        if (isQ) {
            const int b = row >> 8, q = row & 255;
            // qe4 layout: [b][h4 = hg2][q][4] — single coalesced 16B store
            *(float4*)(qe_t + ((size_t)(b * 32 + hg2) * 256 + q) * 4) = e;
        } else {
            *(float4*)(ke + (size_t)row * HD + hg2 * 4) = e;
        }
    }
}

// ---------------------------------------------------------------------------
// attn_kernel v5: 2048 blocks x 256 threads. Block = (b, 2 consecutive k).
//  - k-tile 2 -> 8 blocks/CU x 4 waves = 32 waves/CU (v3 was grid-limited
//    at 16). Occupancy via GRID, not launch-bounds squeeze (v4's spill bug).
//  - qe4 [h/4][q][4] layout: 32 coalesced float4 qv loads (was 128 scalar),
//    components feed v_pk_fma directly (no packing movs).
// Phase 1: thread = q: score[k][q] = sumv - 2*sum_h v[h]*rcp(1 + qe*ke)
// Phase 2: waves 0,1 -> softmax over q for k=w; write attention + attn_T LDS
// Phase 3: wave w -> q-range [w*64,(w+1)*64), both k; LDS reduce -> context
// ---------------------------------------------------------------------------
__global__ __launch_bounds__(256, 8) void attn_kernel(const float* __restrict__ qe_t,
                                                      const float* __restrict__ ke,
                                                      const float* __restrict__ v,
                                                      const float* __restrict__ value,
                                                      float* __restrict__ out)
{
    __shared__ float  score_s[2][260];
    __shared__ float  attn_T[256][2];    // [q][k] -> float2 row per q
    __shared__ float2 partc[4][2][64];   // [wave][k][vd-pair]

    const int t  = threadIdx.x;
    const int b  = blockIdx.x >> 7;
    const int k0 = (blockIdx.x & 127) << 1;

    const float* qeb = qe_t + (size_t)b * (32 * 256 * 4);   // [h4][q][4], e^{2qp}
    const float* kep = ke + ((size_t)b * LK + k0) * HD;     // 2 rows, e^{2kp}

    // ---- Phase 1 ----
    v2f acc0 = (v2f)0.f, acc1 = (v2f)0.f;
    const int q = t;
#pragma unroll 4
    for (int g = 0; g < 32; g++) {       // h = 4g .. 4g+3
        const float4 qv4 = *(const float4*)(qeb + ((size_t)g * 256 + q) * 4);
        const int hA = g * 4;
        const v2f vha = *(const v2f*)(v + hA);          // uniform -> s_load
        const v2f vhb = *(const v2f*)(v + hA + 2);
        v2f q2a; q2a.x = qv4.x; q2a.y = qv4.y;
        v2f q2b; q2b.x = qv4.z; q2b.y = qv4.w;
        {
            const v2f ka = *(const v2f*)(kep + hA);     // uniform
            const v2f kb = *(const v2f*)(kep + hA + 2);
            v2f ta = __builtin_elementwise_fma(q2a, ka, (v2f)1.0f);
            v2f ra; ra.x = fast_rcp(ta.x); ra.y = fast_rcp(ta.y);
            acc0 = __builtin_elementwise_fma(vha, ra, acc0);
            v2f tb = __builtin_elementwise_fma(q2b, kb, (v2f)1.0f);
            v2f rb; rb.x = fast_rcp(tb.x); rb.y = fast_rcp(tb.y);
            acc0 = __builtin_elementwise_fma(vhb, rb, acc0);
        }
        {
            const v2f ka = *(const v2f*)(kep + HD + hA);
            const v2f kb = *(const v2f*)(kep + HD + hA + 2);
            v2f ta = __builtin_elementwise_fma(q2a, ka, (v2f)1.0f);
            v2f ra; ra.x = fast_rcp(ta.x); ra.y = fast_rcp(ta.y);
            acc1 = __builtin_elementwise_fma(vha, ra, acc1);
            v2f tb = __builtin_elementwise_fma(q2b, kb, (v2f)1.0f);
            v2f rb; rb.x = fast_rcp(tb.x); rb.y = fast_rcp(tb.y);
            acc1 = __builtin_elementwise_fma(vhb, rb, acc1);
        }
    }
    float sumv = 0.f;  // wave-uniform, scalar pipe
#pragma unroll
    for (int h = 0; h < HD; h++) sumv += v[h];

    score_s[0][q] = sumv - 2.f * (acc0.x + acc0.y);
    score_s[1][q] = sumv - 2.f * (acc1.x + acc1.y);
    __syncthreads();

    // ---- Phase 2: waves 0,1 -> softmax over q for k = w ----
    const int w = t >> 6, lane = t & 63;
    if (w < 2) {
        float x0 = score_s[w][lane];
        float x1 = score_s[w][lane + 64];
        float x2 = score_s[w][lane + 128];
        float x3 = score_s[w][lane + 192];
        float m = fmaxf(fmaxf(x0, x1), fmaxf(x2, x3));
#pragma unroll
        for (int off = 32; off >= 1; off >>= 1) m = fmaxf(m, __shfl_xor(m, off));
        float e0 = fast_exp2((x0 - m) * L2E);
        float e1 = fast_exp2((x1 - m) * L2E);
        float e2 = fast_exp2((x2 - m) * L2E);
        float e3 = fast_exp2((x3 - m) * L2E);
        float s = e0 + e1 + e2 + e3;
#pragma unroll
        for (int off = 32; off >= 1; off >>= 1) s += __shfl_xor(s, off);
        const float rs = fast_rcp(s);
        e0 *= rs; e1 *= rs; e2 *= rs; e3 *= rs;
        attn_T[lane][w]       = e0;
        attn_T[lane + 64][w]  = e1;
        attn_T[lane + 128][w] = e2;
        attn_T[lane + 192][w] = e3;
        float* ao = out + CTX_SIZE + ((size_t)(b * LK + k0 + w)) * LQ;
        ao[lane]       = e0;
        ao[lane + 64]  = e1;
        ao[lane + 128] = e2;
        ao[lane + 192] = e3;
    }
    __syncthreads();

    // ---- Phase 3: context. Wave w sums q-range [w*64,(w+1)*64) for both k ----
    {
        const int vd2 = lane * 2;
        const float* valb = value + (size_t)b * LQ * VD;
        v2f c0 = (v2f)0.f, c1 = (v2f)0.f;
#pragma unroll 4
        for (int i = 0; i < 64; i++) {
            const int q2 = (w << 6) + i;
            const float2 a = *(const float2*)&attn_T[q2][0];   // uniform -> broadcast
            const v2f vv = *(const v2f*)(valb + (size_t)q2 * VD + vd2);
            c0 = __builtin_elementwise_fma((v2f)(a.x), vv, c0);
            c1 = __builtin_elementwise_fma((v2f)(a.y), vv, c1);
        }
        partc[w][0][lane] = *(const float2*)&c0;
        partc[w][1][lane] = *(const float2*)&c1;
    }
    __syncthreads();
    if (t < 128) {
        const int kg = t >> 6, l2 = t & 63;
        const float2 p0 = partc[0][kg][l2];
        const float2 p1 = partc[1][kg][l2];
        const float2 p2 = partc[2][kg][l2];
        const float2 p3 = partc[3][kg][l2];
        float2 s;
        s.x = p0.x + p1.x + p2.x + p3.x;
        s.y = p0.y + p1.y + p2.y + p3.y;
        *(float2*)(out + ((size_t)(b * LK + k0 + kg)) * VD + l2 * 2) = s;
    }
}

extern "C" void kernel_launch(void* const* d_in, const int* in_sizes, int n_in,
                              void* d_out, int out_size, void* d_ws, size_t ws_size,
                              hipStream_t stream)
{
    const float* query = (const float*)d_in[0];
    const float* key   = (const float*)d_in[1];
    const float* value = (const float*)d_in[2];
    const float* Wq    = (const float*)d_in[3];
    const float* Wk    = (const float*)d_in[4];
    const float* v     = (const float*)d_in[5];
    float* out = (float*)d_out;

    float* qe_t = (float*)d_ws;                      // [B][HD/4][LQ][4], e^{2qp}
    float* kew  = qe_t + (size_t)B_ * HD * LQ;       // [B][LK][HD], e^{2kp}

    proj_kernel<<<dim3(1024), 256, 0, stream>>>(query, key, Wq, Wk, qe_t, kew);
    attn_kernel<<<dim3(2048), 256, 0, stream>>>(qe_t, kew, v, value, out);
}

// Round 6
// 101.917 us; speedup vs baseline: 1.3375x; 1.0402x over previous
//
#include <hip/hip_runtime.h>

#define B_  16
#define LQ  256
#define LK  256
#define QD  256
#define HD  128
#define VD  128

// 2*log2(e): exp2(SCALE2*x) = e^{2x}
#define SCALE2 2.8853900817779268f
#define CTX_SIZE (B_ * LK * VD)

typedef float v2f __attribute__((ext_vector_type(2)));

__device__ __forceinline__ float fast_exp2(float x) { return __builtin_amdgcn_exp2f(x); }
__device__ __forceinline__ float fast_rcp(float x)  { return __builtin_amdgcn_rcpf(x); }

// ---------------------------------------------------------------------------
// proj_kernel: 1024 blocks x 256 threads.
//   blocks [0,512):   qe4[b][h/4][q][4] = exp2(SCALE2 * (query @ Wq))
//   blocks [512,1024): ke[b][k][h]  = exp2(SCALE2 * (key @ Wk))
// ---------------------------------------------------------------------------
__global__ __launch_bounds__(256) void proj_kernel(const float* __restrict__ query,
                                                   const float* __restrict__ key,
                                                   const float* __restrict__ Wq,
                                                   const float* __restrict__ Wk,
                                                   float* __restrict__ qe_t,
                                                   float* __restrict__ ke)
{
    __shared__ float  Xs[8][260];        // 8 rows x full K (=256), padded
    __shared__ float4 part[4][8][32];    // [wave][m][h-group] partial sums

    const int t = threadIdx.x;
    const bool isQ = (blockIdx.x < 512);
    const int blk  = isQ ? blockIdx.x : (blockIdx.x - 512);
    const int rows0 = blk * 8;
    const float* X = isQ ? query : key;
    const float* W = isQ ? Wq : Wk;

    // ---- stage X tile: 8 rows x 256 k (8 KB) ----
    {
        const int r = t >> 5;            // 0..7
        const int c = (t & 31) * 8;      // 0..248
        const float4 x0 = *(const float4*)(X + (size_t)(rows0 + r) * QD + c);
        const float4 x1 = *(const float4*)(X + (size_t)(rows0 + r) * QD + c + 4);
        *(float4*)&Xs[r][c]     = x0;
        *(float4*)&Xs[r][c + 4] = x1;
    }
    __syncthreads();

    const int w    = t >> 6;
    const int lane = t & 63;
    const int hg   = lane & 31;          // h4 = hg*4
    const int mb   = lane >> 5;          // 0/1; lane covers m = mb, mb+2, mb+4, mb+6

    float4 acc[4];
#pragma unroll
    for (int i = 0; i < 4; i++) acc[i] = make_float4(0.f, 0.f, 0.f, 0.f);

    const int kbase = w * 64;
#pragma unroll 4
    for (int kk = 0; kk < 64; kk++) {
        const int k = kbase + kk;
        const float4 wv = *(const float4*)(W + (size_t)k * HD + hg * 4);
#pragma unroll
        for (int mi = 0; mi < 4; mi++) {
            const float xv = Xs[mb + mi * 2][k];
            acc[mi].x += xv * wv.x;
            acc[mi].y += xv * wv.y;
            acc[mi].z += xv * wv.z;
            acc[mi].w += xv * wv.w;
        }
    }
#pragma unroll
    for (int mi = 0; mi < 4; mi++) part[w][mb + mi * 2][hg] = acc[mi];
    __syncthreads();

    // ---- reduce 4 partials, exp, store ----
    {
        const int m   = t >> 5;          // 0..7
        const int hg2 = t & 31;          // 0..31  (covers h = hg2*4 .. +3)
        float4 s = part[0][m][hg2];
        const float4 p1 = part[1][m][hg2];
        const float4 p2 = part[2][m][hg2];
        const float4 p3 = part[3][m][hg2];
        s.x += p1.x + p2.x + p3.x;
        s.y += p1.y + p2.y + p3.y;
        s.z += p1.z + p2.z + p3.z;
        s.w += p1.w + p2.w + p3.w;
        float4 e = make_float4(fast_exp2(s.x * SCALE2), fast_exp2(s.y * SCALE2),
                               fast_exp2(s.z * SCALE2), fast_exp2(s.w * SCALE2));
        const int row = rows0 + m;
        if (isQ) {
            const int b = row >> 8, q = row & 255;
            // qe4 layout: [b][h4 = hg2][q][4] — single coalesced 16B store
            *(float4*)(qe_t + ((size_t)(b * 32 + hg2) * 256 + q) * 4) = e;
        } else {
            *(float4*)(ke + (size_t)row * HD + hg2 * 4) = e;
        }
    }
}

// ---------------------------------------------------------------------------
// attn_kernel v6: 1024 blocks x 256 threads. Block = (b, 4 consecutive k).
//  - PAIRED RECIPROCALS: 1/a,1/b = (b*r, a*r), r=rcp(a*b). Halves the
//    v_rcp count (134M -> 67M) — rcp measured ~16cy/wave is the bottleneck
//    (attn time invariant across occupancy/load variants v1/v3/v5).
//    Overflow-safe: tt <= ~1e7, product <= ~1e14 << 3.4e38.
//  - sumv DROPPED: softmax(sumv - 2a) == softmax(-2a) (shift-invariant);
//    min-reduce acc instead of max-reduce score.
//  - qe4 [h/4][q][4] coalesced float4 loads (from v5); k-tile 4 (v3 grid).
// Phase 1: thread = q: acc[k] = sum_h v[h]*rcp(1 + qe[h][q]*ke[k][h])
// Phase 2: wave w -> softmax over q for k=w; write attention + attn_T LDS
// Phase 3: wave w -> q-range [w*64,(w+1)*64), all 4 k; LDS reduce -> context
// ---------------------------------------------------------------------------
__global__ __launch_bounds__(256) void attn_kernel(const float* __restrict__ qe_t,
                                                   const float* __restrict__ ke,
                                                   const float* __restrict__ v,
                                                   const float* __restrict__ value,
                                                   float* __restrict__ out)
{
    __shared__ float  score_s[4][260];
    __shared__ float  attn_T[256][4];    // [q][k] -> float4 row per q
    __shared__ float2 partc[4][4][64];   // [wave][k][vd-pair]

    const int t  = threadIdx.x;
    const int b  = blockIdx.x >> 6;
    const int k0 = (blockIdx.x & 63) << 2;

    const float* qeb = qe_t + (size_t)b * (32 * 256 * 4);   // [h4][q][4], e^{2qp}
    const float* kep = ke + ((size_t)b * LK + k0) * HD;     // 4 rows, e^{2kp}

    // ---- Phase 1 ----
    float acc0 = 0.f, acc1 = 0.f, acc2 = 0.f, acc3 = 0.f;
    const int q = t;

#define PAIR_STEP(QJ, VJ, KA, KB, KC, KD)                          \
    {                                                              \
        const float t0 = fmaf(QJ, KA, 1.0f);                       \
        const float t1 = fmaf(QJ, KB, 1.0f);                       \
        const float t2 = fmaf(QJ, KC, 1.0f);                       \
        const float t3 = fmaf(QJ, KD, 1.0f);                       \
        const float r01 = fast_rcp(t0 * t1);                       \
        const float r23 = fast_rcp(t2 * t3);                       \
        acc0 = fmaf(VJ * t1, r01, acc0);                           \
        acc1 = fmaf(VJ * t0, r01, acc1);                           \
        acc2 = fmaf(VJ * t3, r23, acc2);                           \
        acc3 = fmaf(VJ * t2, r23, acc3);                           \
    }

#pragma unroll 4
    for (int g = 0; g < 32; g++) {       // h = 4g .. 4g+3
        const float4 qv = *(const float4*)(qeb + ((size_t)g * 256 + q) * 4);
        const int hA = g * 4;
        const float4 va = *(const float4*)(v + hA);             // uniform -> s_load
        const float4 ka = *(const float4*)(kep + hA);           // uniform
        const float4 kb = *(const float4*)(kep + HD + hA);
        const float4 kc = *(const float4*)(kep + 2 * HD + hA);
        const float4 kd = *(const float4*)(kep + 3 * HD + hA);
        PAIR_STEP(qv.x, va.x, ka.x, kb.x, kc.x, kd.x)
        PAIR_STEP(qv.y, va.y, ka.y, kb.y, kc.y, kd.y)
        PAIR_STEP(qv.z, va.z, ka.z, kb.z, kc.z, kd.z)
        PAIR_STEP(qv.w, va.w, ka.w, kb.w, kc.w, kd.w)
    }
#undef PAIR_STEP

    // score = sumv - 2*acc; softmax is shift-invariant -> store raw acc
    score_s[0][q] = acc0;
    score_s[1][q] = acc1;
    score_s[2][q] = acc2;
    score_s[3][q] = acc3;
    __syncthreads();

    // ---- Phase 2: softmax over q, wave w handles k=w.
    //      score = -2*acc -> max(score) == min(acc);
    //      e^{score - max} = exp2((m - acc) * 2*log2e) = exp2((m-acc)*SCALE2)
    const int w = t >> 6, lane = t & 63;
    {
        float x0 = score_s[w][lane];
        float x1 = score_s[w][lane + 64];
        float x2 = score_s[w][lane + 128];
        float x3 = score_s[w][lane + 192];
        float m = fminf(fminf(x0, x1), fminf(x2, x3));
#pragma unroll
        for (int off = 32; off >= 1; off >>= 1) m = fminf(m, __shfl_xor(m, off));
        float e0 = fast_exp2((m - x0) * SCALE2);
        float e1 = fast_exp2((m - x1) * SCALE2);
        float e2 = fast_exp2((m - x2) * SCALE2);
        float e3 = fast_exp2((m - x3) * SCALE2);
        float s = e0 + e1 + e2 + e3;
#pragma unroll
        for (int off = 32; off >= 1; off >>= 1) s += __shfl_xor(s, off);
        const float rs = fast_rcp(s);
        e0 *= rs; e1 *= rs; e2 *= rs; e3 *= rs;
        attn_T[lane][w]       = e0;
        attn_T[lane + 64][w]  = e1;
        attn_T[lane + 128][w] = e2;
        attn_T[lane + 192][w] = e3;
        float* ao = out + CTX_SIZE + ((size_t)(b * LK + k0 + w)) * LQ;
        ao[lane]       = e0;
        ao[lane + 64]  = e1;
        ao[lane + 128] = e2;
        ao[lane + 192] = e3;
    }
    __syncthreads();

    // ---- Phase 3: context. Wave w sums its q-range for all 4 k ----
    {
        const int vd2 = lane * 2;
        const float* valb = value + (size_t)b * LQ * VD;
        v2f c0 = (v2f)0.f, c1 = (v2f)0.f, c2 = (v2f)0.f, c3 = (v2f)0.f;
#pragma unroll 4
        for (int i = 0; i < 64; i++) {
            const int q2 = (w << 6) + i;
            const float4 a = *(const float4*)&attn_T[q2][0];    // uniform -> broadcast
            const v2f vv = *(const v2f*)(valb + (size_t)q2 * VD + vd2);
            c0 = __builtin_elementwise_fma((v2f)(a.x), vv, c0);
            c1 = __builtin_elementwise_fma((v2f)(a.y), vv, c1);
            c2 = __builtin_elementwise_fma((v2f)(a.z), vv, c2);
            c3 = __builtin_elementwise_fma((v2f)(a.w), vv, c3);
        }
        partc[w][0][lane] = *(const float2*)&c0;
        partc[w][1][lane] = *(const float2*)&c1;
        partc[w][2][lane] = *(const float2*)&c2;
        partc[w][3][lane] = *(const float2*)&c3;
    }
    __syncthreads();
    {
        const int kg = t >> 6, l2 = t & 63;
        const float2 p0 = partc[0][kg][l2];
        const float2 p1 = partc[1][kg][l2];
        const float2 p2 = partc[2][kg][l2];
        const float2 p3 = partc[3][kg][l2];
        float2 s;
        s.x = p0.x + p1.x + p2.x + p3.x;
        s.y = p0.y + p1.y + p2.y + p3.y;
        *(float2*)(out + ((size_t)(b * LK + k0 + kg)) * VD + l2 * 2) = s;
    }
}

extern "C" void kernel_launch(void* const* d_in, const int* in_sizes, int n_in,
                              void* d_out, int out_size, void* d_ws, size_t ws_size,
                              hipStream_t stream)
{
    const float* query = (const float*)d_in[0];
    const float* key   = (const float*)d_in[1];
    const float* value = (const float*)d_in[2];
    const float* Wq    = (const float*)d_in[3];
    const float* Wk    = (const float*)d_in[4];
    const float* v     = (const float*)d_in[5];
    float* out = (float*)d_out;

    float* qe_t = (float*)d_ws;                      // [B][HD/4][LQ][4], e^{2qp}
    float* kew  = qe_t + (size_t)B_ * HD * LQ;       // [B][LK][HD], e^{2kp}

    proj_kernel<<<dim3(1024), 256, 0, stream>>>(query, key, Wq, Wk, qe_t, kew);
    attn_kernel<<<dim3(1024), 256, 0, stream>>>(qe_t, kew, v, value, out);
}

// Round 7
// 101.042 us; speedup vs baseline: 1.3491x; 1.0087x over previous
//
#include <hip/hip_runtime.h>

#define B_  16
#define LQ  256
#define LK  256
#define QD  256
#define HD  128
#define VD  128

// 2*log2(e): exp2(SCALE2*x) = e^{2x}
#define SCALE2 2.8853900817779268f
#define CTX_SIZE (B_ * LK * VD)

typedef float v2f __attribute__((ext_vector_type(2)));
typedef float v4f __attribute__((ext_vector_type(4)));

__device__ __forceinline__ float fast_exp2(float x) { return __builtin_amdgcn_exp2f(x); }
__device__ __forceinline__ float fast_rcp(float x)  { return __builtin_amdgcn_rcpf(x); }

// ---------------------------------------------------------------------------
// proj_kernel: 1024 blocks x 256 threads (unchanged — known-good).
//   blocks [0,512):   qe4[b][h/4][q][4] = exp2(SCALE2 * (query @ Wq))
//   blocks [512,1024): ke[b][k][h]  = exp2(SCALE2 * (key @ Wk))
// ---------------------------------------------------------------------------
__global__ __launch_bounds__(256) void proj_kernel(const float* __restrict__ query,
                                                   const float* __restrict__ key,
                                                   const float* __restrict__ Wq,
                                                   const float* __restrict__ Wk,
                                                   float* __restrict__ qe_t,
                                                   float* __restrict__ ke)
{
    __shared__ float  Xs[8][260];        // 8 rows x full K (=256), padded
    __shared__ float4 part[4][8][32];    // [wave][m][h-group] partial sums

    const int t = threadIdx.x;
    const bool isQ = (blockIdx.x < 512);
    const int blk  = isQ ? blockIdx.x : (blockIdx.x - 512);
    const int rows0 = blk * 8;
    const float* X = isQ ? query : key;
    const float* W = isQ ? Wq : Wk;

    // ---- stage X tile: 8 rows x 256 k (8 KB) ----
    {
        const int r = t >> 5;            // 0..7
        const int c = (t & 31) * 8;      // 0..248
        const float4 x0 = *(const float4*)(X + (size_t)(rows0 + r) * QD + c);
        const float4 x1 = *(const float4*)(X + (size_t)(rows0 + r) * QD + c + 4);
        *(float4*)&Xs[r][c]     = x0;
        *(float4*)&Xs[r][c + 4] = x1;
    }
    __syncthreads();

    const int w    = t >> 6;
    const int lane = t & 63;
    const int hg   = lane & 31;          // h4 = hg*4
    const int mb   = lane >> 5;          // 0/1; lane covers m = mb, mb+2, mb+4, mb+6

    float4 acc[4];
#pragma unroll
    for (int i = 0; i < 4; i++) acc[i] = make_float4(0.f, 0.f, 0.f, 0.f);

    const int kbase = w * 64;
#pragma unroll 4
    for (int kk = 0; kk < 64; kk++) {
        const int k = kbase + kk;
        const float4 wv = *(const float4*)(W + (size_t)k * HD + hg * 4);
#pragma unroll
        for (int mi = 0; mi < 4; mi++) {
            const float xv = Xs[mb + mi * 2][k];
            acc[mi].x += xv * wv.x;
            acc[mi].y += xv * wv.y;
            acc[mi].z += xv * wv.z;
            acc[mi].w += xv * wv.w;
        }
    }
#pragma unroll
    for (int mi = 0; mi < 4; mi++) part[w][mb + mi * 2][hg] = acc[mi];
    __syncthreads();

    // ---- reduce 4 partials, exp, store ----
    {
        const int m   = t >> 5;          // 0..7
        const int hg2 = t & 31;          // 0..31  (covers h = hg2*4 .. +3)
        float4 s = part[0][m][hg2];
        const float4 p1 = part[1][m][hg2];
        const float4 p2 = part[2][m][hg2];
        const float4 p3 = part[3][m][hg2];
        s.x += p1.x + p2.x + p3.x;
        s.y += p1.y + p2.y + p3.y;
        s.z += p1.z + p2.z + p3.z;
        s.w += p1.w + p2.w + p3.w;
        float4 e = make_float4(fast_exp2(s.x * SCALE2), fast_exp2(s.y * SCALE2),
                               fast_exp2(s.z * SCALE2), fast_exp2(s.w * SCALE2));
        const int row = rows0 + m;
        if (isQ) {
            const int b = row >> 8, q = row & 255;
            // qe4 layout: [b][h4 = hg2][q][4] — single coalesced 16B store
            *(float4*)(qe_t + ((size_t)(b * 32 + hg2) * 256 + q) * 4) = e;
        } else {
            *(float4*)(ke + (size_t)row * HD + hg2 * 4) = e;
        }
    }
}

// ---------------------------------------------------------------------------
// attn_kernel v7: 1024 blocks x 256 threads. Block = (b, 4 consecutive k).
//  - ke (4x128) + v (128) staged in LDS; inner loop reads them as
//    same-address ds_read_b128 broadcasts on the DS pipe. Removes the
//    uniform VMEM loads from the VMEM/TA pipe (theory: VMEM instruction
//    occupancy, not VALU and not TLP, is the ~23us residual —
//    occupancy-insensitive v3==v5 rules out latency hiding).
//  - Phase 3 on float4: 32 dwordx4 value loads per thread (was 64 dwordx2),
//    lane = (q-parity, vd4-slot), shfl-free LDS reduce over [wave][parity].
//  - Paired reciprocals, min-softmax, qe4 layout (from v6).
// ---------------------------------------------------------------------------
__global__ __launch_bounds__(256) void attn_kernel(const float* __restrict__ qe_t,
                                                   const float* __restrict__ ke,
                                                   const float* __restrict__ v,
                                                   const float* __restrict__ value,
                                                   float* __restrict__ out)
{
    __shared__ float ke_s[4][128];        // 2 KB   e^{2kp} rows k0..k0+3
    __shared__ float v_s[128];            // 0.5 KB
    __shared__ float score_s[4][260];     // 4.1 KB
    __shared__ float attn_T[256][4];      // 4 KB  [q][k]
    __shared__ v4f   partc4[4][4][2][32]; // 16 KB [wave][k][q-parity][vd4]

    const int t  = threadIdx.x;
    const int b  = blockIdx.x >> 6;
    const int k0 = (blockIdx.x & 63) << 2;

    const float* qeb = qe_t + (size_t)b * (32 * 256 * 4);   // [h4][q][4], e^{2qp}
    const float* kep = ke + ((size_t)b * LK + k0) * HD;     // 4 rows, e^{2kp}

    // ---- stage ke + v into LDS (coalesced: 512 + 128 consecutive floats) ----
    ((float*)ke_s)[t]       = kep[t];
    ((float*)ke_s)[t + 256] = kep[t + 256];
    if (t < 128) v_s[t] = v[t];
    __syncthreads();

    // ---- Phase 1 ----
    float acc0 = 0.f, acc1 = 0.f, acc2 = 0.f, acc3 = 0.f;
    const int q = t;

#define PAIR_STEP(QJ, VJ, KA, KB, KC, KD)                          \
    {                                                              \
        const float t0 = fmaf(QJ, KA, 1.0f);                       \
        const float t1 = fmaf(QJ, KB, 1.0f);                       \
        const float t2 = fmaf(QJ, KC, 1.0f);                       \
        const float t3 = fmaf(QJ, KD, 1.0f);                       \
        const float r01 = fast_rcp(t0 * t1);                       \
        const float r23 = fast_rcp(t2 * t3);                       \
        acc0 = fmaf(VJ * t1, r01, acc0);                           \
        acc1 = fmaf(VJ * t0, r01, acc1);                           \
        acc2 = fmaf(VJ * t3, r23, acc2);                           \
        acc3 = fmaf(VJ * t2, r23, acc3);                           \
    }

#pragma unroll 4
    for (int g = 0; g < 32; g++) {       // h = 4g .. 4g+3
        const float4 qv = *(const float4*)(qeb + ((size_t)g * 256 + q) * 4);
        const int hA = g * 4;
        const float4 va = *(const float4*)&v_s[hA];      // LDS broadcast
        const float4 ka = *(const float4*)&ke_s[0][hA];  // LDS broadcast
        const float4 kb = *(const float4*)&ke_s[1][hA];
        const float4 kc = *(const float4*)&ke_s[2][hA];
        const float4 kd = *(const float4*)&ke_s[3][hA];
        PAIR_STEP(qv.x, va.x, ka.x, kb.x, kc.x, kd.x)
        PAIR_STEP(qv.y, va.y, ka.y, kb.y, kc.y, kd.y)
        PAIR_STEP(qv.z, va.z, ka.z, kb.z, kc.z, kd.z)
        PAIR_STEP(qv.w, va.w, ka.w, kb.w, kc.w, kd.w)
    }
#undef PAIR_STEP

    // score = sumv - 2*acc; softmax is shift-invariant -> store raw acc
    score_s[0][q] = acc0;
    score_s[1][q] = acc1;
    score_s[2][q] = acc2;
    score_s[3][q] = acc3;
    __syncthreads();

    // ---- Phase 2: softmax over q, wave w handles k=w.
    //      score = -2*acc -> max(score) == min(acc);
    //      e^{score - max} = exp2((m - acc) * SCALE2)
    const int w = t >> 6, lane = t & 63;
    {
        float x0 = score_s[w][lane];
        float x1 = score_s[w][lane + 64];
        float x2 = score_s[w][lane + 128];
        float x3 = score_s[w][lane + 192];
        float m = fminf(fminf(x0, x1), fminf(x2, x3));
#pragma unroll
        for (int off = 32; off >= 1; off >>= 1) m = fminf(m, __shfl_xor(m, off));
        float e0 = fast_exp2((m - x0) * SCALE2);
        float e1 = fast_exp2((m - x1) * SCALE2);
        float e2 = fast_exp2((m - x2) * SCALE2);
        float e3 = fast_exp2((m - x3) * SCALE2);
        float s = e0 + e1 + e2 + e3;
#pragma unroll
        for (int off = 32; off >= 1; off >>= 1) s += __shfl_xor(s, off);
        const float rs = fast_rcp(s);
        e0 *= rs; e1 *= rs; e2 *= rs; e3 *= rs;
        attn_T[lane][w]       = e0;
        attn_T[lane + 64][w]  = e1;
        attn_T[lane + 128][w] = e2;
        attn_T[lane + 192][w] = e3;
        float* ao = out + CTX_SIZE + ((size_t)(b * LK + k0 + w)) * LQ;
        ao[lane]       = e0;
        ao[lane + 64]  = e1;
        ao[lane + 128] = e2;
        ao[lane + 192] = e3;
    }
    __syncthreads();

    // ---- Phase 3: context, float4 granularity.
    //      lane -> (q-parity qo = lane>>5, vd4 slot = lane&31).
    //      Wave w covers q in [w*64,(w+1)*64): 32 iters x 2 q (by parity).
    {
        const int qo  = lane >> 5;            // 0/1
        const int vdi = lane & 31;            // float4 slot: vd = vdi*4
        const float* valb = value + (size_t)b * LQ * VD;
        v4f c0 = (v4f)0.f, c1 = (v4f)0.f, c2 = (v4f)0.f, c3 = (v4f)0.f;
#pragma unroll 4
        for (int i = 0; i < 32; i++) {
            const int q2 = (w << 6) + (i << 1) + qo;
            const v4f a  = *(const v4f*)&attn_T[q2][0];               // 2-addr broadcast
            const v4f vv = *(const v4f*)(valb + (size_t)q2 * VD + vdi * 4);
            c0 = __builtin_elementwise_fma((v4f)(a.x), vv, c0);
            c1 = __builtin_elementwise_fma((v4f)(a.y), vv, c1);
            c2 = __builtin_elementwise_fma((v4f)(a.z), vv, c2);
            c3 = __builtin_elementwise_fma((v4f)(a.w), vv, c3);
        }
        partc4[w][0][qo][vdi] = c0;
        partc4[w][1][qo][vdi] = c1;
        partc4[w][2][qo][vdi] = c2;
        partc4[w][3][qo][vdi] = c3;
    }
    __syncthreads();
    if (t < 128) {
        const int kg = t >> 5, vdj = t & 31;
        v4f s = (v4f)0.f;
#pragma unroll
        for (int ww = 0; ww < 4; ww++) {
            s += partc4[ww][kg][0][vdj];
            s += partc4[ww][kg][1][vdj];
        }
        *(v4f*)(out + ((size_t)(b * LK + k0 + kg)) * VD + vdj * 4) = s;
    }
}

extern "C" void kernel_launch(void* const* d_in, const int* in_sizes, int n_in,
                              void* d_out, int out_size, void* d_ws, size_t ws_size,
                              hipStream_t stream)
{
    const float* query = (const float*)d_in[0];
    const float* key   = (const float*)d_in[1];
    const float* value = (const float*)d_in[2];
    const float* Wq    = (const float*)d_in[3];
    const float* Wk    = (const float*)d_in[4];
    const float* v     = (const float*)d_in[5];
    float* out = (float*)d_out;

    float* qe_t = (float*)d_ws;                      // [B][HD/4][LQ][4], e^{2qp}
    float* kew  = qe_t + (size_t)B_ * HD * LQ;       // [B][LK][HD], e^{2kp}

    proj_kernel<<<dim3(1024), 256, 0, stream>>>(query, key, Wq, Wk, qe_t, kew);
    attn_kernel<<<dim3(1024), 256, 0, stream>>>(qe_t, kew, v, value, out);
}